// Round 1
// baseline (18.758 us; speedup 1.0000x reference)
//
#include <hip/hip_runtime.h>

// Problem constants (match reference)
#define B_ 16
#define N_ 8192
#define U_ 64        // INPUT_DIM
#define W_ 128       // LATENT_DIM
#define BLOCKS_PER_B 64
#define ROWS_PER_BLOCK (N_ / BLOCKS_PER_B)   // 128

// ws layout: per b, 256 floats: [u][4] where slot 0 = sum feat, slots 1..3 = sum feat*nhat_k
// out layout: [B,512]: w<128 scalar path, 128+3w+k vector path

__global__ __launch_bounds__(256) void so3_reduce_kernel(
    const float* __restrict__ feat,   // [B,N,64]
    const float* __restrict__ pos,    // [B,N,3]
    float* __restrict__ ws)           // [B,64,4] accumulated via atomics (pre-zeroed)
{
    const int blk   = blockIdx.x;              // 0 .. B*BLOCKS_PER_B-1
    const int b     = blk / BLOCKS_PER_B;
    const int chunk = blk % BLOCKS_PER_B;
    const int row0  = chunk * ROWS_PER_BLOCK;
    const int tid   = threadIdx.x;             // 0..255 (4 waves)
    const int grp   = tid & 15;                // feature group: features 4*grp .. 4*grp+3
    const int rsub  = tid >> 4;                // 0..15: row within a 16-row iteration group

    float accS[4] = {0.f, 0.f, 0.f, 0.f};
    float accM[4][3] = {{0.f,0.f,0.f},{0.f,0.f,0.f},{0.f,0.f,0.f},{0.f,0.f,0.f}};

    const float4* fbase = (const float4*)(feat + (size_t)b * N_ * U_);
    const float*  pbase = pos + (size_t)b * N_ * 3;

    for (int it = 0; it < ROWS_PER_BLOCK; it += 16) {
        const int n = row0 + it + rsub;
        // 16 B/lane, wave reads 4 consecutive rows = 1 KiB contiguous
        const float4 f = fbase[(size_t)n * 16 + grp];
        const float px = pbase[n * 3 + 0];
        const float py = pbase[n * 3 + 1];
        const float pz = pbase[n * 3 + 2];
        const float inv = rsqrtf(px * px + py * py + pz * pz);
        const float nx = px * inv, ny = py * inv, nz = pz * inv;

        accS[0] += f.x; accS[1] += f.y; accS[2] += f.z; accS[3] += f.w;
        accM[0][0] += f.x * nx; accM[0][1] += f.x * ny; accM[0][2] += f.x * nz;
        accM[1][0] += f.y * nx; accM[1][1] += f.y * ny; accM[1][2] += f.y * nz;
        accM[2][0] += f.z * nx; accM[2][1] += f.z * ny; accM[2][2] += f.z * nz;
        accM[3][0] += f.w * nx; accM[3][1] += f.w * ny; accM[3][2] += f.w * nz;
    }

    // Block-level combine: each thread dumps 16 accumulators to LDS (pad 17 to
    // break the stride-16 bank pattern), then 256 threads each own one (u, j)
    // output and sum the 16 contributing threads.
    __shared__ float lds[256][17];
    lds[tid][0] = accS[0]; lds[tid][1] = accS[1];
    lds[tid][2] = accS[2]; lds[tid][3] = accS[3];
    #pragma unroll
    for (int i = 0; i < 4; ++i) {
        lds[tid][4 + i * 3 + 0] = accM[i][0];
        lds[tid][4 + i * 3 + 1] = accM[i][1];
        lds[tid][4 + i * 3 + 2] = accM[i][2];
    }
    __syncthreads();

    const int u   = tid >> 2;     // 0..63
    const int j   = tid & 3;      // 0 = S, 1..3 = M[k]
    const int ug  = u >> 2;       // which feature-group (writer grp)
    const int sub = u & 3;        // which of the writer's 4 features
    const int slot = (j == 0) ? sub : (4 + sub * 3 + (j - 1));
    float s = 0.f;
    #pragma unroll
    for (int src = 0; src < 16; ++src) {
        const int t = (src & 3) * 64 + (src >> 2) * 16 + ug;  // wave*64 + riw*16 + ug
        s += lds[t][slot];
    }
    atomicAdd(&ws[b * 256 + u * 4 + j], s);
}

__global__ __launch_bounds__(512) void so3_finalize_kernel(
    const float* __restrict__ ws,   // [B,64,4] sums
    const float* __restrict__ W0,   // [64,128]
    const float* __restrict__ W1,   // [64,128]
    float* __restrict__ out)        // [B,512]
{
    const int b = blockIdx.x;
    const int t = threadIdx.x;      // 0..511

    __shared__ float sm[256];
    if (t < 256) sm[t] = ws[b * 256 + t];
    __syncthreads();

    const float scaleS = 0.125f / (float)N_;                      // PATH_COEFF / N
    const float scaleV = 0.125f * 1.7320508075688772f / (float)N_; // PATH_COEFF*sqrt(3)/N

    float acc = 0.f;
    if (t < 128) {
        #pragma unroll
        for (int u = 0; u < 64; ++u) acc += sm[u * 4] * W0[u * 128 + t];
        out[b * 512 + t] = acc * scaleS;
    } else {
        const int idx = t - 128;       // 0..383
        const int w = idx / 3;
        const int k = idx - 3 * w;
        #pragma unroll
        for (int u = 0; u < 64; ++u) acc += sm[u * 4 + 1 + k] * W1[u * 128 + w];
        out[b * 512 + 128 + idx] = acc * scaleV;
    }
}

extern "C" void kernel_launch(void* const* d_in, const int* in_sizes, int n_in,
                              void* d_out, int out_size, void* d_ws, size_t ws_size,
                              hipStream_t stream) {
    const float* feat = (const float*)d_in[0];
    const float* pos  = (const float*)d_in[1];
    const float* W0   = (const float*)d_in[2];
    const float* W1   = (const float*)d_in[3];
    float* out = (float*)d_out;
    float* ws  = (float*)d_ws;

    // Zero the accumulator region each launch (ws is not re-poisoned between
    // replays; memset node is graph-capture-safe).
    hipMemsetAsync(ws, 0, B_ * 256 * sizeof(float), stream);

    so3_reduce_kernel<<<B_ * BLOCKS_PER_B, 256, 0, stream>>>(feat, pos, ws);
    so3_finalize_kernel<<<B_, 512, 0, stream>>>(ws, W0, W1, out);
}

// Round 2
// 14.199 us; speedup vs baseline: 1.3211x; 1.3211x over previous
//
#include <hip/hip_runtime.h>

// Problem constants (match reference)
#define B_ 16
#define N_ 8192
#define U_ 64        // INPUT_DIM
#define W_ 128       // LATENT_DIM
#define BLOCKS_PER_B 64
#define ROWS_PER_BLOCK (N_ / BLOCKS_PER_B)   // 128

// ws layout: [B*BLOCKS_PER_B][256] block-partial sums.
//   slot tid encodes (u = tid>>2, j = tid&3); j==0 -> sum feat_u, j=1..3 -> sum feat_u * nhat_{j-1}
// out layout: [B,512]: w<128 scalar path, 128+3w+k vector path

__global__ __launch_bounds__(256) void so3_reduce_kernel(
    const float* __restrict__ feat,   // [B,N,64]
    const float* __restrict__ pos,    // [B,N,3]
    float* __restrict__ ws)           // [B*64][256] partials (written, not accumulated)
{
    const int blk   = blockIdx.x;              // 0 .. B*BLOCKS_PER_B-1
    const int b     = blk / BLOCKS_PER_B;
    const int chunk = blk % BLOCKS_PER_B;
    const int row0  = chunk * ROWS_PER_BLOCK;
    const int tid   = threadIdx.x;             // 0..255 (4 waves)
    const int grp   = tid & 15;                // feature group: features 4*grp .. 4*grp+3
    const int rsub  = tid >> 4;                // 0..15: row within a 16-row iteration group

    float accS[4] = {0.f, 0.f, 0.f, 0.f};
    float accM[4][3] = {{0.f,0.f,0.f},{0.f,0.f,0.f},{0.f,0.f,0.f},{0.f,0.f,0.f}};

    const float4* fbase = (const float4*)(feat + (size_t)b * N_ * U_);
    const float*  pbase = pos + (size_t)b * N_ * 3;

    #pragma unroll
    for (int it = 0; it < ROWS_PER_BLOCK; it += 16) {
        const int n = row0 + it + rsub;
        // 16 B/lane; a wave reads 4 consecutive rows = 1 KiB contiguous
        const float4 f = fbase[(size_t)n * 16 + grp];
        const float px = pbase[n * 3 + 0];
        const float py = pbase[n * 3 + 1];
        const float pz = pbase[n * 3 + 2];
        const float inv = rsqrtf(px * px + py * py + pz * pz);
        const float nx = px * inv, ny = py * inv, nz = pz * inv;

        accS[0] += f.x; accS[1] += f.y; accS[2] += f.z; accS[3] += f.w;
        accM[0][0] += f.x * nx; accM[0][1] += f.x * ny; accM[0][2] += f.x * nz;
        accM[1][0] += f.y * nx; accM[1][1] += f.y * ny; accM[1][2] += f.y * nz;
        accM[2][0] += f.z * nx; accM[2][1] += f.z * ny; accM[2][2] += f.z * nz;
        accM[3][0] += f.w * nx; accM[3][1] += f.w * ny; accM[3][2] += f.w * nz;
    }

    // Block-level combine: each thread dumps its 16 accumulators to LDS (pad
    // to 17 to break the stride-16 bank pattern); then 256 threads each own
    // one (u, j) slot and sum the 16 contributing threads.
    __shared__ float lds[256][17];
    lds[tid][0] = accS[0]; lds[tid][1] = accS[1];
    lds[tid][2] = accS[2]; lds[tid][3] = accS[3];
    #pragma unroll
    for (int i = 0; i < 4; ++i) {
        lds[tid][4 + i * 3 + 0] = accM[i][0];
        lds[tid][4 + i * 3 + 1] = accM[i][1];
        lds[tid][4 + i * 3 + 2] = accM[i][2];
    }
    __syncthreads();

    const int u   = tid >> 2;     // 0..63
    const int j   = tid & 3;      // 0 = S, 1..3 = M[k]
    const int ug  = u >> 2;       // which feature-group (writer grp)
    const int sub = u & 3;        // which of the writer's 4 features
    const int slot = (j == 0) ? sub : (4 + sub * 3 + (j - 1));
    float s = 0.f;
    #pragma unroll
    for (int src = 0; src < 16; ++src) {
        const int t = (src & 3) * 64 + (src >> 2) * 16 + ug;  // wave*64 + row-in-wave*16 + ug
        s += lds[t][slot];
    }
    // Coalesced 1 KiB partial store; no atomics, no pre-zero required.
    ws[(size_t)blk * 256 + tid] = s;
}

__global__ __launch_bounds__(512) void so3_finalize_kernel(
    const float* __restrict__ ws,   // [B*64][256] partials
    const float* __restrict__ W0,   // [64,128]
    const float* __restrict__ W1,   // [64,128]
    float* __restrict__ out)        // [B,512]
{
    const int b   = blockIdx.x;
    const int tid = threadIdx.x;    // 0..511

    __shared__ float sm2[512];
    __shared__ float sm[256];

    // Phase 1: cross-block combine. 512 threads: (slot = tid&255, half = tid>>8)
    // each sums 32 of the 64 chunk-partials; loads are coalesced (256
    // consecutive floats per chunk).
    {
        const int slot = tid & 255;
        const int half = tid >> 8;
        const float* base = ws + ((size_t)b * BLOCKS_PER_B + half * 32) * 256;
        float s = 0.f;
        #pragma unroll
        for (int c = 0; c < 32; ++c) s += base[(size_t)c * 256 + slot];
        sm2[tid] = s;
    }
    __syncthreads();
    if (tid < 256) sm[tid] = sm2[tid] + sm2[tid + 256];
    __syncthreads();

    // Phase 2: tiny matmul, one output element per thread.
    const float scaleS = 0.125f / (float)N_;                       // PATH_COEFF / N
    const float scaleV = 0.125f * 1.7320508075688772f / (float)N_; // PATH_COEFF*sqrt(3)/N

    float acc = 0.f;
    if (tid < 128) {
        #pragma unroll
        for (int u = 0; u < 64; ++u) acc += sm[u * 4] * W0[u * 128 + tid];
        out[b * 512 + tid] = acc * scaleS;
    } else {
        const int idx = tid - 128;     // 0..383
        const int w = idx / 3;
        const int k = idx - 3 * w;
        #pragma unroll
        for (int u = 0; u < 64; ++u) acc += sm[u * 4 + 1 + k] * W1[u * 128 + w];
        out[b * 512 + 128 + idx] = acc * scaleV;
    }
}

extern "C" void kernel_launch(void* const* d_in, const int* in_sizes, int n_in,
                              void* d_out, int out_size, void* d_ws, size_t ws_size,
                              hipStream_t stream) {
    const float* feat = (const float*)d_in[0];
    const float* pos  = (const float*)d_in[1];
    const float* W0   = (const float*)d_in[2];
    const float* W1   = (const float*)d_in[3];
    float* out = (float*)d_out;
    float* ws  = (float*)d_ws;   // needs B*64*256*4 = 1 MiB of scratch

    so3_reduce_kernel<<<B_ * BLOCKS_PER_B, 256, 0, stream>>>(feat, pos, ws);
    so3_finalize_kernel<<<B_, 512, 0, stream>>>(ws, W0, W1, out);
}